// Round 9
// baseline (476.731 us; speedup 1.0000x reference)
//
#include <hip/hip_runtime.h>

// FilterBank: x (128,22,2000) f32, a,b (9,9) f32 -> y (128,22,9,2000) f32
// y[t] = sum_k bn[k] x[t-k] - sum_{k>=1} an[k] y[t-k], zero init state.
//
// R9: single fused kernel, exact chunk-scan via decoupled lookback.
// Per block (g=seq group of 64, c=time chunk of 128):
//   phase A: run chunk from zero y-state (exact x history) -> end state st
//   publish st + flag (release, agent scope)
//   M = A^128 computed in-block (72 threads) while last wave polls
//     predecessor flags (acquire); Horner: s_init = sum M^{c-1-j} st_j
//   phase C: re-run chunk from s_init, write y via swizzled-LDS staging
// Liveness: ticket-ordered virtual block ids (blocks that start first get
// lower vid; phase A never waits) + grid 704 <= 768 resident (3 blk/CU at
// 54.3 KB LDS). flags/ticket zeroed per launch by hipMemsetAsync.
// step16 / M recurrence / Horner / staging swizzle verbatim from R8 (exact,
// absmax 0.0078125 verified).

#define TT 2000
#define KK 9
#define NB 9
#define LCH 128
#define NCHUNK 16
#define BLK 576
#define XP3 68         // x sub-tile row stride (64 data + pad)

__device__ __forceinline__ float rfl(float v) {
    return __uint_as_float(__builtin_amdgcn_readfirstlane(__float_as_uint(v)));
}

// ---- 16-step IIR core ----
__device__ __forceinline__ void step16(const float* an, const float* bn,
                                       const float* xc, float* yc,
                                       float* xh, float* yh)
{
#pragma unroll
    for (int i = 0; i < 16; ++i) {
        float s = bn[0] * xc[i];
#pragma unroll
        for (int k = 1; k < KK; ++k) {
            const float xt = (i - k >= 0) ? xc[i - k] : xh[k - i - 1];
            s = fmaf(bn[k], xt, s);
        }
#pragma unroll
        for (int k = 2; k < KK; ++k) {
            const float yt = (i - k >= 0) ? yc[i - k] : yh[k - i - 1];
            s = fmaf(-an[k], yt, s);
        }
        const float y1 = (i >= 1) ? yc[i - 1] : yh[0];
        yc[i] = fmaf(-an[1], y1, s);   // cross-step critical path = 1 FMA
    }
#pragma unroll
    for (int m = 0; m < 8; ++m) { xh[m] = xc[15 - m]; yh[m] = yc[15 - m]; }
}

__device__ __forceinline__ void load_coeffs_sgpr(const float* a, const float* b,
                                                 int w, float* an, float* bn)
{
    const float inv = rfl(1.0f / a[w * KK]);
#pragma unroll
    for (int k = 0; k < KK; ++k) {
        an[k] = rfl(a[w * KK + k] * inv);
        bn[k] = rfl(b[w * KK + k] * inv);
    }
}

__device__ __forceinline__ void unpack16(const float4* xb, float* xc)
{
    float4 v0 = xb[0], v1 = xb[1], v2 = xb[2], v3 = xb[3];
    xc[0]=v0.x; xc[1]=v0.y; xc[2]=v0.z; xc[3]=v0.w;
    xc[4]=v1.x; xc[5]=v1.y; xc[6]=v1.z; xc[7]=v1.w;
    xc[8]=v2.x; xc[9]=v2.y; xc[10]=v2.z; xc[11]=v2.w;
    xc[12]=v3.x; xc[13]=v3.y; xc[14]=v3.z; xc[15]=v3.w;
}

// cooperative 64-step sub-tile load: rows [seq0,seq0+64) x [ts, ts+64)
__device__ __forceinline__ void load_subtile(const float* __restrict__ x,
                                             float* xs, int seq0, int ts, int tid)
{
#pragma unroll
    for (int u = 0; u < 2; ++u) {
        const int i4 = tid + u * BLK;
        if (i4 < 1024) {
            const int rr = i4 >> 4, j4 = i4 & 15;
            const int gt = ts + j4 * 4;
            float4 v = make_float4(0.f, 0.f, 0.f, 0.f);
            if (gt <= TT - 4)
                v = *(const float4*)(x + (size_t)(seq0 + rr) * TT + gt);
            *(float4*)(&xs[rr * XP3 + j4 * 4]) = v;
        }
    }
}

__global__ __launch_bounds__(BLK, 7) void fb_fused(
    const float* __restrict__ x, const float* __restrict__ a,
    const float* __restrict__ b, float* __restrict__ y,
    float* __restrict__ st, int* __restrict__ flags,
    int* __restrict__ ticket, int nfil)
{
    __shared__ float xs[64 * XP3];       // 17408 B
    __shared__ float ys[BLK * 16];       // 36864 B: hist[0:512], M[512:1088],
                                         //          then phase-C staging
    __shared__ int vid_s;

    const int tid = threadIdx.x;
    if (tid == 0) vid_s = atomicAdd(ticket, 1);   // start-ordered virtual id
    __syncthreads();
    const int vid  = vid_s;
    const int c    = vid & (NCHUNK - 1);
    const int g    = vid >> 4;
    const int seq0 = g * 64;
    const int t0   = c * LCH;
    const int t_end = (t0 + LCH < TT) ? t0 + LCH : TT;
    const int nit  = (t_end - t0) >> 4;           // 8 or 5
    const int ni1  = nit - 4;                     // 4 or 1

    // x history x[t0-8..t0-1] -> ys[0:512]
    if (tid < 128) {
        const int hr = tid >> 1, part = tid & 1;
        const int gt = t0 - 8 + part * 4;
        float4 v = make_float4(0.f, 0.f, 0.f, 0.f);
        if (gt >= 0)
            v = *(const float4*)(x + (size_t)(seq0 + hr) * TT + gt);
        *(float4*)(&ys[hr * 8 + part * 4]) = v;
    }
    load_subtile(x, xs, seq0, t0, tid);

    const int w = __builtin_amdgcn_readfirstlane(tid >> 6);   // band
    const int r = tid & 63;
    const int fil = (seq0 + r) * NB + w;

    float an[KK], bn[KK];
    load_coeffs_sgpr(a, b, w, an, bn);

    __syncthreads();

    float h[8];                               // keep x history in regs
    {
        float4 h0 = *(const float4*)(&ys[r * 8]);
        float4 h1 = *(const float4*)(&ys[r * 8 + 4]);
        h[0]=h1.w; h[1]=h1.z; h[2]=h1.y; h[3]=h1.x;
        h[4]=h0.w; h[5]=h0.z; h[6]=h0.y; h[7]=h0.x;
    }

    // ---- phase A: chunk from zero y-state ----
    float xh[8], yh[8];
#pragma unroll
    for (int m = 0; m < 8; ++m) { xh[m] = h[m]; yh[m] = 0.f; }

    for (int il = 0; il < 4; ++il) {
        float xc[16], yc[16];
        unpack16((const float4*)(&xs[r * XP3 + il * 16]), xc);
        step16(an, bn, xc, yc, xh, yh);
    }
    __syncthreads();
    load_subtile(x, xs, seq0, t0 + 64, tid);
    __syncthreads();
    for (int il = 0; il < ni1; ++il) {
        float xc[16], yc[16];
        unpack16((const float4*)(&xs[r * XP3 + il * 16]), xc);
        step16(an, bn, xc, yc, xh, yh);
    }

    // ---- publish end state + flag ----
    {
        float4* sv = (float4*)(st + ((size_t)c * nfil + fil) * 8);
        sv[0] = make_float4(yh[0], yh[1], yh[2], yh[3]);
        sv[1] = make_float4(yh[4], yh[5], yh[6], yh[7]);
    }
    __threadfence();
    __syncthreads();
    if (tid == 0)
        __hip_atomic_store(&flags[vid], 1, __ATOMIC_RELEASE,
                           __HIP_MEMORY_SCOPE_AGENT);

    // ---- poll predecessors (last wave) while computing M (first 72) ----
    if (tid >= 512 && (tid - 512) < c) {
        while (__hip_atomic_load(&flags[(vid - c) + (tid - 512)],
                                 __ATOMIC_ACQUIRE,
                                 __HIP_MEMORY_SCOPE_AGENT) == 0)
            __builtin_amdgcn_s_sleep(8);
    }
    if (tid < NB * 8) {                       // M = A^LCH, column per thread
        const int band = tid >> 3, j = tid & 7;
        float am[KK];
        const float inv = 1.0f / a[band * KK];
#pragma unroll
        for (int k = 0; k < KK; ++k) am[k] = a[band * KK + k] * inv;
        float v[8] = {0.f,0.f,0.f,0.f,0.f,0.f,0.f,0.f};
        v[j] = 1.0f;
        for (int t = 0; t < LCH; ++t) {
            float s = 0.f;
#pragma unroll
            for (int k = 1; k < KK; ++k) s = fmaf(-am[k], v[k - 1], s);
#pragma unroll
            for (int m = 7; m >= 1; --m) v[m] = v[m - 1];
            v[0] = s;
        }
#pragma unroll
        for (int m = 0; m < 8; ++m) ys[512 + band * 64 + m * 8 + j] = v[m];
    }
    __syncthreads();                          // flags seen + M ready

    // ---- Horner: s_init = sum_{j<c} M^{c-1-j} st_j ----
    float s0[8] = {0.f,0.f,0.f,0.f,0.f,0.f,0.f,0.f};
    {
        const float* Mb = &ys[512 + w * 64];  // wave-uniform base (broadcast)
        for (int j = 0; j < c; ++j) {
            const float4* ep = (const float4*)(st + ((size_t)j * nfil + fil) * 8);
            float4 e0 = ep[0], e1 = ep[1];
            const float e[8] = {e0.x,e0.y,e0.z,e0.w, e1.x,e1.y,e1.z,e1.w};
            float ns[8];
#pragma unroll
            for (int m = 0; m < 8; ++m) {
                float acc = e[m];
#pragma unroll
                for (int k = 0; k < 8; ++k) acc = fmaf(Mb[m * 8 + k], s0[k], acc);
                ns[m] = acc;
            }
#pragma unroll
            for (int m = 0; m < 8; ++m) s0[m] = ns[m];
        }
    }
    __syncthreads();                          // M consumed; ys free for staging

    // ---- phase C: chunk from exact init state, write y ----
    load_subtile(x, xs, seq0, t0, tid);
    __syncthreads();

#pragma unroll
    for (int m = 0; m < 8; ++m) { xh[m] = h[m]; yh[m] = s0[m]; }

    const int q   = r >> 2;                   // 0..15
    const int cc  = r & 3;
    const int rot = (r >> 1) & 3;             // write-side rotate
    const int qh  = (q >> 1) & 3;             // read-side rotate

    int itg = 0;
    for (int s2 = 0; s2 < 2; ++s2) {
        if (s2) {
            __syncthreads();
            load_subtile(x, xs, seq0, t0 + 64, tid);
            __syncthreads();
        }
        const int ni = s2 ? ni1 : 4;
        for (int il = 0; il < ni; ++il, ++itg) {
            float xc[16], yc[16];
            unpack16((const float4*)(&xs[r * XP3 + il * 16]), xc);
            step16(an, bn, xc, yc, xh, yh);

            // stage own row, rotate-swizzled (wave-private region)
            float4* yl = (float4*)(&ys[(w * 64 + r) * 16]);
            yl[(0 + rot) & 3] = make_float4(yc[0],  yc[1],  yc[2],  yc[3]);
            yl[(1 + rot) & 3] = make_float4(yc[4],  yc[5],  yc[6],  yc[7]);
            yl[(2 + rot) & 3] = make_float4(yc[8],  yc[9],  yc[10], yc[11]);
            yl[(3 + rot) & 3] = make_float4(yc[12], yc[13], yc[14], yc[15]);
            asm volatile("s_waitcnt lgkmcnt(0)" ::: "memory");

            // transposed store: 4 lanes per filter -> full 64B lines
#pragma unroll
            for (int s3 = 0; s3 < 4; ++s3) {
                const int row = s3 * 16 + q;
                const int p   = (cc + qh) & 3;
                float4 v = *(const float4*)(&ys[(w * 64 + row) * 16 + p * 4]);
                float* dst = y + ((size_t)(seq0 + row) * NB + w) * TT
                               + t0 + itg * 16 + cc * 4;
                *(float4*)dst = v;
            }
        }
    }
}

// ---- fallback: exact thread-per-filter, full length ----
__global__ __launch_bounds__(64) void fb_fallback(
    const float* __restrict__ x, const float* __restrict__ a,
    const float* __restrict__ b, float* __restrict__ y, int nfil)
{
    const int tid = blockIdx.x * 64 + threadIdx.x;
    if (tid >= nfil) return;
    const int seq  = tid / NB;
    const int band = tid - seq * NB;

    const float* xp = x + (size_t)seq * TT;
    float*       yp = y + (size_t)tid * TT;

    float an[KK], bn[KK];
    const float inv = 1.0f / a[band * KK];
#pragma unroll
    for (int k = 0; k < KK; ++k) {
        an[k] = a[band * KK + k] * inv;
        bn[k] = b[band * KK + k] * inv;
    }

    float xh[8] = {0.f,0.f,0.f,0.f,0.f,0.f,0.f,0.f};
    float yh[8] = {0.f,0.f,0.f,0.f,0.f,0.f,0.f,0.f};

    for (int t0 = 0; t0 < TT; t0 += 16) {
        float xc[16], yc[16];
        unpack16((const float4*)(xp + t0), xc);
        step16(an, bn, xc, yc, xh, yh);
        float4* yv = (float4*)(yp + t0);
        yv[0] = make_float4(yc[0],  yc[1],  yc[2],  yc[3]);
        yv[1] = make_float4(yc[4],  yc[5],  yc[6],  yc[7]);
        yv[2] = make_float4(yc[8],  yc[9],  yc[10], yc[11]);
        yv[3] = make_float4(yc[12], yc[13], yc[14], yc[15]);
    }
}

extern "C" void kernel_launch(void* const* d_in, const int* in_sizes, int n_in,
                              void* d_out, int out_size, void* d_ws, size_t ws_size,
                              hipStream_t stream) {
    const float* x = (const float*)d_in[0];
    const float* a = (const float*)d_in[1];
    const float* b = (const float*)d_in[2];
    float*       y = (float*)d_out;

    const int nseq = in_sizes[0] / TT;      // 2816
    const int nfil = nseq * NB;             // 25344

    const int grid = (nseq / 64) * NCHUNK;  // 44*16 = 704
    const size_t need = 4096 + (size_t)NCHUNK * nfil * 8 * 4;   // ~13 MB
    if ((nseq % 64) != 0 || need > ws_size || (size_t)(64 + grid * 4) > 4096) {
        fb_fallback<<<(nfil + 63) / 64, 64, 0, stream>>>(x, a, b, y, nfil);
        return;
    }

    // ws layout: [0:4) ticket | [64 : 64+grid*4) flags | [4096 : ) states
    hipMemsetAsync(d_ws, 0, 4096, stream);  // zero ticket + flags (capture-safe)
    int*   ticket = (int*)d_ws;
    int*   flags  = (int*)d_ws + 16;
    float* st     = (float*)((char*)d_ws + 4096);

    fb_fused<<<grid, BLK, 0, stream>>>(x, a, b, y, st, flags, ticket, nfil);
}

// Round 10
// 286.571 us; speedup vs baseline: 1.6636x; 1.6636x over previous
//
#include <hip/hip_runtime.h>

// FilterBank: x (128,22,2000) f32, a,b (9,9) f32 -> y (128,22,9,2000) f32
// y[t] = sum_k bn[k] x[t-k] - sum_{k>=1} a n[k] y[t-k], zero init state.
//
// R10: ONE kernel, no inter-block coordination. Chunk init state computed
// per-block as a 336-tap truncated-FIR of x with the band's impulse
// response h (336 >= R3's measured-safe 320-step warm-up):
//   y[t0-1-m] = sum_{tau<336} h[tau] x[t0-1-m-tau],  m=0..7
// Block (g = 64 seqs, c = 128-step chunk), 576 thr = 9 waves (wave==band):
//   1. build h[336] per band in ys LDS (~2k cyc, waves in parallel)
//   2. FIR: 7 x 48-tap segments over LDS-staged x (8 ILP-rich accs)
//   3. exact 128-step chunk; y stores via R8's verified rotate-swizzled
//      LDS staging -> full 64B lines
// LDS 14336(xs,stride 56: 2-way=free) + 36864(ys) = 51200 -> 3 blk/CU,
// all 704 blocks resident (27 waves/CU). No workspace, no memset.

#define TT 2000
#define KK 9
#define NB 9
#define LCH 128
#define NCHUNK 16
#define BLK 576
#define NTAP 336
#define XST 56         // xs row stride (floats)

__device__ __forceinline__ float rfl(float v) {
    return __uint_as_float(__builtin_amdgcn_readfirstlane(__float_as_uint(v)));
}

// ---- 16-step IIR core ----
__device__ __forceinline__ void step16(const float* an, const float* bn,
                                       const float* xc, float* yc,
                                       float* xh, float* yh)
{
#pragma unroll
    for (int i = 0; i < 16; ++i) {
        float s = bn[0] * xc[i];
#pragma unroll
        for (int k = 1; k < KK; ++k) {
            const float xt = (i - k >= 0) ? xc[i - k] : xh[k - i - 1];
            s = fmaf(bn[k], xt, s);
        }
#pragma unroll
        for (int k = 2; k < KK; ++k) {
            const float yt = (i - k >= 0) ? yc[i - k] : yh[k - i - 1];
            s = fmaf(-an[k], yt, s);
        }
        const float y1 = (i >= 1) ? yc[i - 1] : yh[0];
        yc[i] = fmaf(-an[1], y1, s);   // cross-step critical path = 1 FMA
    }
#pragma unroll
    for (int m = 0; m < 8; ++m) { xh[m] = xc[15 - m]; yh[m] = yc[15 - m]; }
}

__device__ __forceinline__ void load_coeffs_sgpr(const float* a, const float* b,
                                                 int w, float* an, float* bn)
{
    const float inv = rfl(1.0f / a[w * KK]);
#pragma unroll
    for (int k = 0; k < KK; ++k) {
        an[k] = rfl(a[w * KK + k] * inv);
        bn[k] = rfl(b[w * KK + k] * inv);
    }
}

__device__ __forceinline__ void unpack16(const float4* xb, float* xc)
{
    float4 v0 = xb[0], v1 = xb[1], v2 = xb[2], v3 = xb[3];
    xc[0]=v0.x; xc[1]=v0.y; xc[2]=v0.z; xc[3]=v0.w;
    xc[4]=v1.x; xc[5]=v1.y; xc[6]=v1.z; xc[7]=v1.w;
    xc[8]=v2.x; xc[9]=v2.y; xc[10]=v2.z; xc[11]=v2.w;
    xc[12]=v3.x; xc[13]=v3.y; xc[14]=v3.z; xc[15]=v3.w;
}

__global__ __launch_bounds__(BLK, 7) void fb_fir(
    const float* __restrict__ x, const float* __restrict__ a,
    const float* __restrict__ b, float* __restrict__ y, int nfil)
{
    __shared__ float xs[64 * XST];       // 14336 B
    __shared__ float ys[BLK * 16];       // 36864 B: h[0:3024) in FIR phase,
                                         //          staging in main phase
    const int tid  = threadIdx.x;
    const int c    = blockIdx.x & (NCHUNK - 1);
    const int g    = blockIdx.x >> 4;
    const int seq0 = g * 64;
    const int t0   = c * LCH;
    const int t_end = (t0 + LCH < TT) ? t0 + LCH : TT;

    const int w = __builtin_amdgcn_readfirstlane(tid >> 6);   // band
    const int r = tid & 63;

    float an[KK], bn[KK];
    load_coeffs_sgpr(a, b, w, an, bn);

    // ---- 1. impulse response h[0..335] of band w -> ys[w*336 ..) ----
    {
        float hv[12];
#pragma unroll
        for (int t = 0; t < 12; ++t) {
            float s = (t < KK) ? bn[t] : 0.f;
#pragma unroll
            for (int k = 1; k < KK; ++k)
                if (k <= t) s = fmaf(-an[k], hv[t - k], s);
            hv[t] = s;
        }
        if (r == 0) {
            *(float4*)(&ys[w * NTAP + 0]) = make_float4(hv[0], hv[1], hv[2],  hv[3]);
            *(float4*)(&ys[w * NTAP + 4]) = make_float4(hv[4], hv[5], hv[6],  hv[7]);
            *(float4*)(&ys[w * NTAP + 8]) = make_float4(hv[8], hv[9], hv[10], hv[11]);
        }
        float hh[8];
#pragma unroll
        for (int i = 0; i < 8; ++i) hh[i] = hv[11 - i];
        for (int bq = 0; bq < (NTAP - 12) / 4; ++bq) {
            float nv[4];
#pragma unroll
            for (int d = 0; d < 4; ++d) {
                float s = 0.f;
#pragma unroll
                for (int k = 1; k < KK; ++k) s = fmaf(-an[k], hh[k - 1], s);
#pragma unroll
                for (int m = 7; m >= 1; --m) hh[m] = hh[m - 1];
                hh[0] = s;
                nv[d] = s;
            }
            if (r == 0)
                *(float4*)(&ys[w * NTAP + 12 + bq * 4]) =
                    make_float4(nv[0], nv[1], nv[2], nv[3]);
        }
    }

    // ---- 2. FIR boundary states: acc[m] = y[t0-1-m], m=0..7 ----
    float acc[8] = {0.f,0.f,0.f,0.f,0.f,0.f,0.f,0.f};
    float xh[8];
    __syncthreads();                          // h table visible

    for (int s = 6; s >= 0; --s) {
        // tile = x[t0-56-48s .. t0-1-48s], 56 floats/row, 64 rows
        const int base_t = t0 - XST - 48 * s;
#pragma unroll
        for (int u = 0; u < 2; ++u) {
            const int i4 = tid + u * BLK;
            if (i4 < 896) {
                const int rr = i4 / 14, j4 = i4 - rr * 14;
                const int gt = base_t + j4 * 4;
                float4 v = make_float4(0.f, 0.f, 0.f, 0.f);
                if (gt >= 0)
                    v = *(const float4*)(x + (size_t)(seq0 + rr) * TT + gt);
                *(float4*)(&xs[rr * XST + j4 * 4]) = v;
            }
        }
        __syncthreads();                      // tile ready

        const float* hrow = &ys[w * NTAP + 48 * s];   // wave-uniform
        const float* xr   = &xs[r * XST];
        float4 c2 = *(const float4*)(xr + 52);        // tile[52..55]
        float4 c1 = *(const float4*)(xr + 48);
        float4 c0 = *(const float4*)(xr + 44);
#pragma unroll
        for (int g4 = 0; g4 < 12; ++g4) {
            float4 hq = *(const float4*)(hrow + g4 * 4);
            const float hqa[4] = {hq.x, hq.y, hq.z, hq.w};
            float4 cn = c0;
            if (g4 < 11) cn = *(const float4*)(xr + 40 - g4 * 4);
#pragma unroll
            for (int d = 0; d < 4; ++d) {
                // tau = 48s + 4g4 + d; acc[m] += h[tau]*x[t0-1-m-tau]
#pragma unroll
                for (int m = 0; m < 8; ++m) {
                    const int e = d + m;      // compile-time
                    const float xv = (e <= 3) ? ((const float*)&c2)[3 - e]
                                   : (e <= 7) ? ((const float*)&c1)[7 - e]
                                              : ((const float*)&c0)[11 - e];
                    acc[m] = fmaf(hqa[d], xv, acc[m]);
                }
            }
            c2 = c1; c1 = c0; c0 = cn;
        }
        if (s == 0) {                         // x history from last tile
            float4 t1 = *(const float4*)(xr + 52);    // tile[52..55]
            float4 t2 = *(const float4*)(xr + 48);    // tile[48..51]
            xh[0]=t1.w; xh[1]=t1.z; xh[2]=t1.y; xh[3]=t1.x;
            xh[4]=t2.w; xh[5]=t2.z; xh[6]=t2.y; xh[7]=t2.x;
        }
        __syncthreads();                      // consumers done before overwrite
    }

    // ---- 3. exact chunk from FIR init state, write y ----
    float yh[8];
#pragma unroll
    for (int m = 0; m < 8; ++m) yh[m] = acc[m];

    const int q   = r >> 2;                   // 0..15
    const int cc  = r & 3;
    const int rot = (r >> 1) & 3;             // write-side rotate
    const int qh  = (q >> 1) & 3;             // read-side rotate

    int itg = 0;
    for (int ts = t0; ts < t_end; ts += 48) {
        // sub-tile x[ts .. ts+48)
#pragma unroll
        for (int u = 0; u < 2; ++u) {
            const int i4 = tid + u * BLK;
            if (i4 < 768) {
                const int rr = i4 / 12, j4 = i4 - rr * 12;
                const int gt = ts + j4 * 4;
                float4 v = make_float4(0.f, 0.f, 0.f, 0.f);
                if (gt <= TT - 4)
                    v = *(const float4*)(x + (size_t)(seq0 + rr) * TT + gt);
                *(float4*)(&xs[rr * XST + j4 * 4]) = v;
            }
        }
        __syncthreads();                      // tile ready (also: h dead now)

        const int rem = t_end - ts;
        const int ni  = ((rem < 48) ? rem : 48) >> 4;
        for (int il = 0; il < ni; ++il, ++itg) {
            float xc[16], yc[16];
            unpack16((const float4*)(&xs[r * XST + il * 16]), xc);
            step16(an, bn, xc, yc, xh, yh);

            // stage own row, rotate-swizzled (wave-private region)
            float4* yl = (float4*)(&ys[(w * 64 + r) * 16]);
            yl[(0 + rot) & 3] = make_float4(yc[0],  yc[1],  yc[2],  yc[3]);
            yl[(1 + rot) & 3] = make_float4(yc[4],  yc[5],  yc[6],  yc[7]);
            yl[(2 + rot) & 3] = make_float4(yc[8],  yc[9],  yc[10], yc[11]);
            yl[(3 + rot) & 3] = make_float4(yc[12], yc[13], yc[14], yc[15]);
            asm volatile("s_waitcnt lgkmcnt(0)" ::: "memory");

            // transposed store: 4 lanes per filter -> full 64B lines
#pragma unroll
            for (int s3 = 0; s3 < 4; ++s3) {
                const int row = s3 * 16 + q;
                const int p   = (cc + qh) & 3;
                float4 v = *(const float4*)(&ys[(w * 64 + row) * 16 + p * 4]);
                float* dst = y + ((size_t)(seq0 + row) * NB + w) * TT
                               + t0 + itg * 16 + cc * 4;
                *(float4*)dst = v;
            }
        }
        __syncthreads();                      // all reads done before next tile
    }
}

// ---- fallback: exact thread-per-filter, full length ----
__global__ __launch_bounds__(64) void fb_fallback(
    const float* __restrict__ x, const float* __restrict__ a,
    const float* __restrict__ b, float* __restrict__ y, int nfil)
{
    const int tid = blockIdx.x * 64 + threadIdx.x;
    if (tid >= nfil) return;
    const int seq  = tid / NB;
    const int band = tid - seq * NB;

    const float* xp = x + (size_t)seq * TT;
    float*       yp = y + (size_t)tid * TT;

    float an[KK], bn[KK];
    const float inv = 1.0f / a[band * KK];
#pragma unroll
    for (int k = 0; k < KK; ++k) {
        an[k] = a[band * KK + k] * inv;
        bn[k] = b[band * KK + k] * inv;
    }

    float xh[8] = {0.f,0.f,0.f,0.f,0.f,0.f,0.f,0.f};
    float yh[8] = {0.f,0.f,0.f,0.f,0.f,0.f,0.f,0.f};

    for (int t0 = 0; t0 < TT; t0 += 16) {
        float xc[16], yc[16];
        unpack16((const float4*)(xp + t0), xc);
        step16(an, bn, xc, yc, xh, yh);
        float4* yv = (float4*)(yp + t0);
        yv[0] = make_float4(yc[0],  yc[1],  yc[2],  yc[3]);
        yv[1] = make_float4(yc[4],  yc[5],  yc[6],  yc[7]);
        yv[2] = make_float4(yc[8],  yc[9],  yc[10], yc[11]);
        yv[3] = make_float4(yc[12], yc[13], yc[14], yc[15]);
    }
}

extern "C" void kernel_launch(void* const* d_in, const int* in_sizes, int n_in,
                              void* d_out, int out_size, void* d_ws, size_t ws_size,
                              hipStream_t stream) {
    const float* x = (const float*)d_in[0];
    const float* a = (const float*)d_in[1];
    const float* b = (const float*)d_in[2];
    float*       y = (float*)d_out;

    const int nseq = in_sizes[0] / TT;      // 2816
    const int nfil = nseq * NB;             // 25344

    if ((nseq % 64) != 0) {
        fb_fallback<<<(nfil + 63) / 64, 64, 0, stream>>>(x, a, b, y, nfil);
        return;
    }

    const int grid = (nseq / 64) * NCHUNK;  // 44*16 = 704
    fb_fir<<<grid, BLK, 0, stream>>>(x, a, b, y, nfil);
}

// Round 12
// 111.869 us; speedup vs baseline: 4.2615x; 2.5617x over previous
//
#include <hip/hip_runtime.h>

// FilterBank: x (128,22,2000) f32, a,b (9,9) f32 -> y (128,22,9,2000) f32
// y[t] = sum_k bn[k] x[t-k] - sum_{k>=1} an[k] y[t-k], zero init state.
//
// R11 (resubmit; previous round died on infra): R3's proven skeleton
// (warm-up chunks, wave-interleaved, direct global loads, per-thread
// own-row stores -- measured 1x HBM writes, 0 conflicts) + v_pk_fma_f32
// packing: each lane runs TWO filters (same band, adjacent seqs) with
// f32x2 state, so the 17 taps/step issue as 17 pk-FMAs.
// NCHUNK=16, LCH=128, WARM=256 (R3 measured WARM=320 bit-exact vs exact
// scan; 256 keeps trunc <= ~1e-5 rel at +3sigma pole radius 0.956).
// 3168 waves = 3.09/SIMD. No LDS, no barriers, single kernel.

#define TT 2000
#define KK 9
#define NB 9
#define LCH 128
#define NCHUNK 16
#define WARM 256

typedef __attribute__((ext_vector_type(2))) float f32x2;

__device__ __forceinline__ f32x2 fma2(float c, f32x2 v, f32x2 s) {
#if __has_builtin(__builtin_elementwise_fma)
    f32x2 cc = c;                      // splat
    return __builtin_elementwise_fma(cc, v, s);
#else
    f32x2 r; r.x = fmaf(c, v.x, s.x); r.y = fmaf(c, v.y, s.y); return r;
#endif
}

__global__ __launch_bounds__(256, 3) void fb_pk(
    const float* __restrict__ x, const float* __restrict__ a,
    const float* __restrict__ b, float* __restrict__ y)
{
    const int gid  = blockIdx.x * 256 + threadIdx.x;
    const int Wv   = gid >> 6;               // wave [0, 3168)
    const int lane = gid & 63;
    const int c    = Wv & (NCHUNK - 1);      // chunk, wave-interleaved
    const int fw   = Wv >> 4;                // [0, 198)
    const int e    = fw * 64 + lane;         // pair-filter id [0, 12672)
    const int p    = e / NB;                 // seq pair [0, 1408)
    const int w    = e - p * NB;             // band
    const int sa   = 2 * p;                  // even seq; odd = sa+1

    const int t0 = c * LCH;
    const int te = (t0 + LCH < TT) ? t0 + LCH : TT;
    const int s0 = (t0 > WARM) ? t0 - WARM : 0;     // mult of 16
    const int nw = (t0 - s0) >> 4;           // warm-up 16-blocks
    const int nit = (te - s0) >> 4;          // total 16-blocks

    float an[KK], bn[KK];
    {
        const float inv = 1.0f / a[w * KK];
#pragma unroll
        for (int k = 0; k < KK; ++k) {
            an[k] = a[w * KK + k] * inv;
            bn[k] = b[w * KK + k] * inv;
        }
    }

    const float4* xa = (const float4*)(x + (size_t)sa * TT + s0);
    const float4* xb = (const float4*)(x + (size_t)(sa + 1) * TT + s0);
    float4* ya = (float4*)(y + ((size_t)sa * NB + w) * TT + t0);
    float4* yb = (float4*)(y + ((size_t)(sa + 1) * NB + w) * TT + t0);

    f32x2 xh[8], yh[8];
#pragma unroll
    for (int m = 0; m < 8; ++m) { xh[m] = 0.f; yh[m] = 0.f; }

    for (int it = 0; it < nit; ++it) {
        const float4 a0 = xa[it*4+0], a1 = xa[it*4+1],
                     a2 = xa[it*4+2], a3 = xa[it*4+3];
        const float4 b0 = xb[it*4+0], b1 = xb[it*4+1],
                     b2 = xb[it*4+2], b3 = xb[it*4+3];

        f32x2 xc[16], yc[16];
        xc[0]  = (f32x2){a0.x, b0.x}; xc[1]  = (f32x2){a0.y, b0.y};
        xc[2]  = (f32x2){a0.z, b0.z}; xc[3]  = (f32x2){a0.w, b0.w};
        xc[4]  = (f32x2){a1.x, b1.x}; xc[5]  = (f32x2){a1.y, b1.y};
        xc[6]  = (f32x2){a1.z, b1.z}; xc[7]  = (f32x2){a1.w, b1.w};
        xc[8]  = (f32x2){a2.x, b2.x}; xc[9]  = (f32x2){a2.y, b2.y};
        xc[10] = (f32x2){a2.z, b2.z}; xc[11] = (f32x2){a2.w, b2.w};
        xc[12] = (f32x2){a3.x, b3.x}; xc[13] = (f32x2){a3.y, b3.y};
        xc[14] = (f32x2){a3.z, b3.z}; xc[15] = (f32x2){a3.w, b3.w};

#pragma unroll
        for (int i = 0; i < 16; ++i) {
            f32x2 s = xc[i] * bn[0];
#pragma unroll
            for (int k = 1; k < KK; ++k) {
                const f32x2 xt = (i - k >= 0) ? xc[i - k] : xh[k - i - 1];
                s = fma2(bn[k], xt, s);
            }
#pragma unroll
            for (int k = 2; k < KK; ++k) {
                const f32x2 yt = (i - k >= 0) ? yc[i - k] : yh[k - i - 1];
                s = fma2(-an[k], yt, s);
            }
            const f32x2 y1 = (i >= 1) ? yc[i - 1] : yh[0];
            yc[i] = fma2(-an[1], y1, s);   // cross-step critical path = 1 pk-FMA
        }

        if (it >= nw) {                    // main region (wave-uniform)
            const int o = (it - nw) * 4;
            ya[o+0] = make_float4(yc[0].x,  yc[1].x,  yc[2].x,  yc[3].x);
            ya[o+1] = make_float4(yc[4].x,  yc[5].x,  yc[6].x,  yc[7].x);
            ya[o+2] = make_float4(yc[8].x,  yc[9].x,  yc[10].x, yc[11].x);
            ya[o+3] = make_float4(yc[12].x, yc[13].x, yc[14].x, yc[15].x);
            yb[o+0] = make_float4(yc[0].y,  yc[1].y,  yc[2].y,  yc[3].y);
            yb[o+1] = make_float4(yc[4].y,  yc[5].y,  yc[6].y,  yc[7].y);
            yb[o+2] = make_float4(yc[8].y,  yc[9].y,  yc[10].y, yc[11].y);
            yb[o+3] = make_float4(yc[12].y, yc[13].y, yc[14].y, yc[15].y);
        }

#pragma unroll
        for (int m = 0; m < 8; ++m) { xh[m] = xc[15 - m]; yh[m] = yc[15 - m]; }
    }
}

// ---- fallback: exact thread-per-filter, full length (R1 design) ----
__global__ __launch_bounds__(64) void fb_fallback(
    const float* __restrict__ x, const float* __restrict__ a,
    const float* __restrict__ b, float* __restrict__ y, int nfil)
{
    const int tid = blockIdx.x * 64 + threadIdx.x;
    if (tid >= nfil) return;
    const int seq  = tid / NB;
    const int band = tid - seq * NB;

    const float* xp = x + (size_t)seq * TT;
    float*       yp = y + (size_t)tid * TT;

    float an[KK], bn[KK];
    const float inv = 1.0f / a[band * KK];
#pragma unroll
    for (int k = 0; k < KK; ++k) {
        an[k] = a[band * KK + k] * inv;
        bn[k] = b[band * KK + k] * inv;
    }

    float xh[8] = {0.f,0.f,0.f,0.f,0.f,0.f,0.f,0.f};
    float yh[8] = {0.f,0.f,0.f,0.f,0.f,0.f,0.f,0.f};

    for (int t0 = 0; t0 < TT; t0 += 16) {
        float xc[16], yc[16];
        const float4* xv = (const float4*)(xp + t0);
        float4 v0 = xv[0], v1 = xv[1], v2 = xv[2], v3 = xv[3];
        xc[0]=v0.x; xc[1]=v0.y; xc[2]=v0.z; xc[3]=v0.w;
        xc[4]=v1.x; xc[5]=v1.y; xc[6]=v1.z; xc[7]=v1.w;
        xc[8]=v2.x; xc[9]=v2.y; xc[10]=v2.z; xc[11]=v2.w;
        xc[12]=v3.x; xc[13]=v3.y; xc[14]=v3.z; xc[15]=v3.w;
#pragma unroll
        for (int i = 0; i < 16; ++i) {
            float s = bn[0] * xc[i];
#pragma unroll
            for (int k = 1; k < KK; ++k) {
                const float xt = (i - k >= 0) ? xc[i - k] : xh[k - i - 1];
                s = fmaf(bn[k], xt, s);
            }
#pragma unroll
            for (int k = 2; k < KK; ++k) {
                const float yt = (i - k >= 0) ? yc[i - k] : yh[k - i - 1];
                s = fmaf(-an[k], yt, s);
            }
            const float y1 = (i >= 1) ? yc[i - 1] : yh[0];
            yc[i] = fmaf(-an[1], y1, s);
        }
        float4* yv = (float4*)(yp + t0);
        yv[0] = make_float4(yc[0],  yc[1],  yc[2],  yc[3]);
        yv[1] = make_float4(yc[4],  yc[5],  yc[6],  yc[7]);
        yv[2] = make_float4(yc[8],  yc[9],  yc[10], yc[11]);
        yv[3] = make_float4(yc[12], yc[13], yc[14], yc[15]);
#pragma unroll
        for (int m = 0; m < 8; ++m) { xh[m] = xc[15 - m]; yh[m] = yc[15 - m]; }
    }
}

extern "C" void kernel_launch(void* const* d_in, const int* in_sizes, int n_in,
                              void* d_out, int out_size, void* d_ws, size_t ws_size,
                              hipStream_t stream) {
    const float* x = (const float*)d_in[0];
    const float* a = (const float*)d_in[1];
    const float* b = (const float*)d_in[2];
    float*       y = (float*)d_out;

    const int nseq = in_sizes[0] / TT;      // 2816
    const int nfil = nseq * NB;             // 25344

    // need: nseq even, and (nseq/2)*9 a multiple of 64 (pair-filter waves)
    const int npair_f = (nseq / 2) * NB;    // 12672
    if ((nseq & 1) || (npair_f & 63)) {
        fb_fallback<<<(nfil + 63) / 64, 64, 0, stream>>>(x, a, b, y, nfil);
        return;
    }

    const int nwaves = (npair_f / 64) * NCHUNK;   // 198*16 = 3168
    const int grid   = nwaves * 64 / 256;         // 792
    fb_pk<<<grid, 256, 0, stream>>>(x, a, b, y);
}